// Round 4
// baseline (1017.550 us; speedup 1.0000x reference)
//
#include <hip/hip_runtime.h>
#include <math.h>

// KGATConv: N=50000, E=800000, D=64, R=16, fp32.
// R4: same plan as R3, with bf16 handled as raw ushort bits (this ROCm's
// __hip_bfloat16 lacks .data). proj stored bf16 (L3-resident, half gather
// bytes) + parallel edge att pass (2 edges/wave) + light CSR aggregation
// with fused bi-interaction epilogue.

#define DIM 64

__device__ __forceinline__ float4 f4fma(const float4 w, const float s, float4 acc) {
    acc.x = fmaf(w.x, s, acc.x);
    acc.y = fmaf(w.y, s, acc.y);
    acc.z = fmaf(w.z, s, acc.z);
    acc.w = fmaf(w.w, s, acc.w);
    return acc;
}
__device__ __forceinline__ float4 f4zero() { return make_float4(0.f, 0.f, 0.f, 0.f); }

__device__ __forceinline__ unsigned short f2bf(float x) {
    unsigned u = __float_as_uint(x);
    u += 0x7FFFu + ((u >> 16) & 1u);   // round-to-nearest-even
    return (unsigned short)(u >> 16);
}
__device__ __forceinline__ float bf2f(unsigned short b) {
    return __uint_as_float((unsigned)b << 16);
}

__device__ __forceinline__ float fast_tanh(float x) {
    // tanh(x) = 1 - 2/(exp(2x)+1); exp via HW v_exp.
    float ex = __expf(2.0f * x);
    return 1.0f - 2.0f / (ex + 1.0f);
}

// ---------------------------------------------------------------------------
// proj[r,n,:] = bf16( nfeat[n,:] @ relW[r,:,:] )
// ---------------------------------------------------------------------------
__global__ __launch_bounds__(256) void k_proj(const float* __restrict__ nfeat,
                                              const float* __restrict__ relW,
                                              unsigned short* __restrict__ proj,
                                              int N) {
    __shared__ float4 shW[64 * 16];
    __shared__ float4 shNF[64 * 17];

    const int tx = threadIdx.x;
    const int r = blockIdx.y;
    const int n0 = blockIdx.x * 64;

    const float4* Wr = (const float4*)(relW + (size_t)r * DIM * DIM);
#pragma unroll
    for (int i = 0; i < 4; ++i) shW[tx + 256 * i] = Wr[tx + 256 * i];

    const float4* nf4 = (const float4*)(nfeat + (size_t)n0 * DIM);
#pragma unroll
    for (int i = 0; i < 4; ++i) {
        int idx = tx + 256 * i;
        int row = idx >> 4, c = idx & 15;
        float4 v = (n0 + row < N) ? nf4[idx] : f4zero();
        shNF[row * 17 + c] = v;
    }
    __syncthreads();

    const int cidx = tx & 15;
    const int q4 = (tx >> 4) * 4;

    float4 acc[4] = {f4zero(), f4zero(), f4zero(), f4zero()};
#pragma unroll
    for (int d0 = 0; d0 < 64; d0 += 4) {
        float4 w0 = shW[(d0 + 0) * 16 + cidx];
        float4 w1 = shW[(d0 + 1) * 16 + cidx];
        float4 w2 = shW[(d0 + 2) * 16 + cidx];
        float4 w3 = shW[(d0 + 3) * 16 + cidx];
#pragma unroll
        for (int k = 0; k < 4; ++k) {
            float4 nf = shNF[(q4 + k) * 17 + (d0 >> 2)];
            acc[k] = f4fma(w0, nf.x, acc[k]);
            acc[k] = f4fma(w1, nf.y, acc[k]);
            acc[k] = f4fma(w2, nf.z, acc[k]);
            acc[k] = f4fma(w3, nf.w, acc[k]);
        }
    }

    // store 4 bf16 per thread (8B), coalesced
    ushort4* outp = (ushort4*)(proj + ((size_t)r * N + n0) * DIM);
#pragma unroll
    for (int k = 0; k < 4; ++k) {
        int node = q4 + k;
        if (n0 + node >= N) continue;
        ushort4 o;
        o.x = f2bf(acc[k].x);
        o.y = f2bf(acc[k].y);
        o.z = f2bf(acc[k].z);
        o.w = f2bf(acc[k].w);
        outp[node * 16 + cidx] = o;
    }
}

// ---------------------------------------------------------------------------
// CSR build: histogram -> single-block scan -> fill
// ---------------------------------------------------------------------------
__global__ __launch_bounds__(256) void k_hist(const int* __restrict__ dst,
                                              int* __restrict__ deg, int E) {
    int e = blockIdx.x * 256 + threadIdx.x;
    if (e < E) atomicAdd(&deg[dst[e]], 1);
}

__global__ __launch_bounds__(1024) void k_scan(const int* __restrict__ deg,
                                               int* __restrict__ off,
                                               int* __restrict__ cursor,
                                               int N, int E) {
    __shared__ int part[1024];
    const int t = threadIdx.x;
    const int chunk = (N + 1023) / 1024;
    const int s0 = t * chunk;
    const int s1 = min(s0 + chunk, N);

    int sum = 0;
    for (int i = s0; i < s1; ++i) sum += deg[i];
    part[t] = sum;
    __syncthreads();
    for (int d = 1; d < 1024; d <<= 1) {
        int other = (t >= d) ? part[t - d] : 0;
        __syncthreads();
        part[t] += other;
        __syncthreads();
    }
    int run = part[t] - sum;
    for (int i = s0; i < s1; ++i) {
        off[i] = run;
        cursor[i] = run;
        run += deg[i];
    }
    if (t == 0) off[N] = E;
}

__global__ __launch_bounds__(256) void k_fill(const int* __restrict__ dst,
                                              int* __restrict__ cursor,
                                              int* __restrict__ eidx, int E) {
    int e = blockIdx.x * 256 + threadIdx.x;
    if (e >= E) return;
    int p = atomicAdd(&cursor[dst[e]], 1);
    eidx[p] = e;
}

// ---------------------------------------------------------------------------
// Parallel edge attention: att[e] = dot(t, tanh(h + ef)), segmax via atomicMax
// on order-preserving keys. One wave handles TWO edges; edges in original
// order so the efeat stream is sequential.
// ---------------------------------------------------------------------------
__global__ __launch_bounds__(256) void k_att(const unsigned short* __restrict__ proj,
                                             const float* __restrict__ efeat,
                                             const int* __restrict__ src,
                                             const int* __restrict__ dst,
                                             const int* __restrict__ etype,
                                             float* __restrict__ att,
                                             unsigned* __restrict__ segmax,
                                             int N, int E) {
    const int wid = blockIdx.x * 4 + (threadIdx.x >> 6);
    const int lane = threadIdx.x & 63;
    const int e0 = wid * 2;
    const int e1 = e0 + 1;
    if (e0 >= E) return;
    const bool has1 = (e1 < E);

    int s0 = src[e0], d0 = dst[e0], r0 = etype[e0];
    int s1 = has1 ? src[e1] : s0;
    int d1 = has1 ? dst[e1] : d0;
    int r1 = has1 ? etype[e1] : r0;

    float t0 = bf2f(proj[((size_t)r0 * N + s0) * DIM + lane]);
    float h0 = bf2f(proj[((size_t)r0 * N + d0) * DIM + lane]);
    float t1 = bf2f(proj[((size_t)r1 * N + s1) * DIM + lane]);
    float h1 = bf2f(proj[((size_t)r1 * N + d1) * DIM + lane]);
    float ef0 = efeat[(size_t)e0 * DIM + lane];
    float ef1 = has1 ? efeat[(size_t)e1 * DIM + lane] : 0.f;

    float a0 = t0 * fast_tanh(h0 + ef0);
    float a1 = t1 * fast_tanh(h1 + ef1);
#pragma unroll
    for (int m = 32; m; m >>= 1) {
        a0 += __shfl_xor(a0, m);
        a1 += __shfl_xor(a1, m);
    }
    if (lane == 0) {
        att[e0] = a0;
        unsigned b0 = __float_as_uint(a0);
        atomicMax(&segmax[d0], b0 ^ (unsigned)(((int)b0 >> 31) | 0x80000000));
        if (has1) {
            att[e1] = a1;
            unsigned b1 = __float_as_uint(a1);
            atomicMax(&segmax[d1], b1 ^ (unsigned)(((int)b1 >> 31) | 0x80000000));
        }
    }
}

// ---------------------------------------------------------------------------
// Per-node softmax aggregation + bi-interaction epilogue. Wave per node.
// ---------------------------------------------------------------------------
__global__ __launch_bounds__(256) void k_aggB(const float* __restrict__ att,
                                              const unsigned* __restrict__ segmax,
                                              const float* __restrict__ nfeat,
                                              const int* __restrict__ src,
                                              const int* __restrict__ off,
                                              const int* __restrict__ eidx,
                                              const float* __restrict__ W1,
                                              const float* __restrict__ W2,
                                              float* __restrict__ hn,
                                              float* __restrict__ out,
                                              int N) {
    const int node = blockIdx.x * 4 + (threadIdx.x >> 6);
    if (node >= N) return;
    const int lane = threadIdx.x & 63;

    const int jb = off[node];
    const int je = off[node + 1];

    unsigned key = segmax[node];
    unsigned bits = (key & 0x80000000u) ? (key ^ 0x80000000u) : ~key;
    const float m = __uint_as_float(bits);

    float l = 0.f, acc = 0.f;
    for (int j = jb; j < je; ++j) {
        const int e = eidx[j];
        const int s = src[e];
        float p = __expf(att[e] - m);
        l += p;
        acc = fmaf(p, nfeat[(size_t)s * DIM + lane], acc);
    }

    const float hval = (je > jb) ? acc / l : 0.f;
    hn[(size_t)node * DIM + lane] = hval;

    const float nf = nfeat[(size_t)node * DIM + lane];
    const float v1 = nf + hval;
    const float v2 = nf * hval;
    float o1 = 0.f, o2 = 0.f;
#pragma unroll 8
    for (int d = 0; d < DIM; ++d) {
        float s1 = __shfl(v1, d);
        float s2 = __shfl(v2, d);
        o1 = fmaf(s1, W1[d * DIM + lane], o1);
        o2 = fmaf(s2, W2[d * DIM + lane], o2);
    }
    out[(size_t)node * DIM + lane] =
        (o1 >= 0.f ? o1 : 0.01f * o1) + (o2 >= 0.f ? o2 : 0.01f * o2);
}

extern "C" void kernel_launch(void* const* d_in, const int* in_sizes, int n_in,
                              void* d_out, int out_size, void* d_ws, size_t ws_size,
                              hipStream_t stream) {
    const float* nfeat = (const float*)d_in[0];
    const float* efeat = (const float*)d_in[1];
    const float* relW  = (const float*)d_in[2];
    const float* W1    = (const float*)d_in[3];
    const float* W2    = (const float*)d_in[4];
    const int* src   = (const int*)d_in[5];
    const int* dst   = (const int*)d_in[6];
    const int* etype = (const int*)d_in[7];

    const int N = in_sizes[0] / DIM;
    const int E = in_sizes[5];
    const int R = in_sizes[2] / (DIM * DIM);

    float* out = (float*)d_out;
    float* hn  = out;                      // output 0: h_neighbor (N x 64)
    float* bi  = out + (size_t)N * DIM;    // output 1: out (N x 64)

    // ws: proj bf16 (R*N*64 ushort) | deg[N] | segmax[N] | off[N+1] | cursor[N] | eidx[E] | att[E]
    unsigned short* proj = (unsigned short*)d_ws;
    size_t projElems = (size_t)R * N * DIM;
    int* deg         = (int*)(proj + projElems);
    unsigned* segmax = (unsigned*)(deg + N);
    int* off         = (int*)(segmax + N);
    int* cursor      = off + (N + 1);
    int* eidx        = cursor + N;
    float* att       = (float*)(eidx + E);

    (void)hipMemsetAsync(deg, 0, (size_t)2 * N * sizeof(int), stream);  // deg + segmax

    k_hist<<<(E + 255) / 256, 256, 0, stream>>>(dst, deg, E);
    k_scan<<<1, 1024, 0, stream>>>(deg, off, cursor, N, E);
    k_fill<<<(E + 255) / 256, 256, 0, stream>>>(dst, cursor, eidx, E);

    dim3 gProj((N + 63) / 64, R);
    k_proj<<<gProj, 256, 0, stream>>>(nfeat, relW, proj, N);

    k_att<<<(E / 2 + 3) / 4 + 1, 256, 0, stream>>>(proj, efeat, src, dst, etype,
                                                   att, segmax, N, E);

    k_aggB<<<(N + 3) / 4, 256, 0, stream>>>(att, segmax, nfeat, src, off, eidx,
                                            W1, W2, hn, bi, N);
}

// Round 5
// 794.591 us; speedup vs baseline: 1.2806x; 1.2806x over previous
//
#include <hip/hip_runtime.h>
#include <math.h>

// KGATConv: N=50000, E=800000, D=64, R=16, fp32.
// R5: k_proj moved to MFMA (fp16 in, fp32 acc, bf16 out) — R4's fp32 vector
// version was latency-bound at 240 VGPR / 11.6% occupancy. Rest unchanged.

#define DIM 64
#define PA 72   // LDS fp16 row stride: 144 B keeps 16-B alignment, rotates banks by 4/row

typedef _Float16 half8 __attribute__((ext_vector_type(8)));
typedef float f32x4 __attribute__((ext_vector_type(4)));

__device__ __forceinline__ float4 f4zero() { return make_float4(0.f, 0.f, 0.f, 0.f); }

__device__ __forceinline__ unsigned short f2bf(float x) {
    unsigned u = __float_as_uint(x);
    u += 0x7FFFu + ((u >> 16) & 1u);   // RNE
    return (unsigned short)(u >> 16);
}
__device__ __forceinline__ float bf2f(unsigned short b) {
    return __uint_as_float((unsigned)b << 16);
}

__device__ __forceinline__ float fast_tanh(float x) {
    float ex = __expf(2.0f * x);
    return 1.0f - 2.0f / (ex + 1.0f);
}

// ---------------------------------------------------------------------------
// proj[r,n,:] = bf16( nfeat[n,:] @ relW[r,:,:] )  via mfma_f32_16x16x32_f16.
// Block: 64-node tile x 1 relation; wave w owns M-tile rows w*16..w*16+15.
// ---------------------------------------------------------------------------
__global__ __launch_bounds__(256) void k_proj(const float* __restrict__ nfeat,
                                              const float* __restrict__ relW,
                                              unsigned short* __restrict__ proj,
                                              int N) {
    __shared__ _Float16 shA[64 * PA];   // nfeat tile [row][k]
    __shared__ _Float16 shB[64 * PA];   // W^T [col][k]

    const int tx = threadIdx.x;
    const int r = blockIdx.y;
    const int n0 = blockIdx.x * 64;

    // stage nfeat tile fp32 -> fp16 (coalesced float4 reads)
    const float4* nf4 = (const float4*)(nfeat + (size_t)n0 * DIM);
#pragma unroll
    for (int i = 0; i < 4; ++i) {
        int idx = tx + 256 * i;              // 64 rows x 16 f4-cols
        int row = idx >> 4, c = idx & 15;
        float4 v = (n0 + row < N) ? nf4[idx] : f4zero();
        _Float16* p = &shA[row * PA + c * 4];
        p[0] = (_Float16)v.x; p[1] = (_Float16)v.y;
        p[2] = (_Float16)v.z; p[3] = (_Float16)v.w;
    }
    // stage W^T: global [d][e] row-major -> LDS [e][d] fp16 (one-time scatter)
    const float4* Wr4 = (const float4*)(relW + (size_t)r * DIM * DIM);
#pragma unroll
    for (int i = 0; i < 4; ++i) {
        int idx = tx + 256 * i;
        int d = idx >> 4, c = (idx & 15) * 4;
        float4 v = Wr4[idx];
        shB[(c + 0) * PA + d] = (_Float16)v.x;
        shB[(c + 1) * PA + d] = (_Float16)v.y;
        shB[(c + 2) * PA + d] = (_Float16)v.z;
        shB[(c + 3) * PA + d] = (_Float16)v.w;
    }
    __syncthreads();

    const int w = tx >> 6;
    const int lane = tx & 63;
    const int lm = lane & 15;
    const int lq = lane >> 4;
    const int m0 = w * 16;

    // A-frags: A[m=lm][k=lq*8+j] for the two k-steps
    half8 a0 = *(const half8*)&shA[(m0 + lm) * PA + 0 * 32 + lq * 8];
    half8 a1 = *(const half8*)&shA[(m0 + lm) * PA + 1 * 32 + lq * 8];

    f32x4 acc[4];
#pragma unroll
    for (int ct = 0; ct < 4; ++ct) {
        half8 b0 = *(const half8*)&shB[(ct * 16 + lm) * PA + 0 * 32 + lq * 8];
        half8 b1 = *(const half8*)&shB[(ct * 16 + lm) * PA + 1 * 32 + lq * 8];
        f32x4 c = {0.f, 0.f, 0.f, 0.f};
        c = __builtin_amdgcn_mfma_f32_16x16x32_f16(a0, b0, c, 0, 0, 0);
        c = __builtin_amdgcn_mfma_f32_16x16x32_f16(a1, b1, c, 0, 0, 0);
        acc[ct] = c;
    }

    // store: D[row=lq*4+i][col=ct*16+lm] -> proj bf16
    unsigned short* projR = proj + ((size_t)r * N + n0) * DIM;
#pragma unroll
    for (int ct = 0; ct < 4; ++ct) {
#pragma unroll
        for (int i = 0; i < 4; ++i) {
            int row = m0 + lq * 4 + i;
            int col = ct * 16 + lm;
            if (n0 + row < N)
                projR[(size_t)row * DIM + col] = f2bf(acc[ct][i]);
        }
    }
}

// ---------------------------------------------------------------------------
// CSR build: histogram -> single-block scan -> fill
// ---------------------------------------------------------------------------
__global__ __launch_bounds__(256) void k_hist(const int* __restrict__ dst,
                                              int* __restrict__ deg, int E) {
    int e = blockIdx.x * 256 + threadIdx.x;
    if (e < E) atomicAdd(&deg[dst[e]], 1);
}

__global__ __launch_bounds__(1024) void k_scan(const int* __restrict__ deg,
                                               int* __restrict__ off,
                                               int* __restrict__ cursor,
                                               int N, int E) {
    __shared__ int part[1024];
    const int t = threadIdx.x;
    const int chunk = (N + 1023) / 1024;
    const int s0 = t * chunk;
    const int s1 = min(s0 + chunk, N);

    int sum = 0;
    for (int i = s0; i < s1; ++i) sum += deg[i];
    part[t] = sum;
    __syncthreads();
    for (int d = 1; d < 1024; d <<= 1) {
        int other = (t >= d) ? part[t - d] : 0;
        __syncthreads();
        part[t] += other;
        __syncthreads();
    }
    int run = part[t] - sum;
    for (int i = s0; i < s1; ++i) {
        off[i] = run;
        cursor[i] = run;
        run += deg[i];
    }
    if (t == 0) off[N] = E;
}

__global__ __launch_bounds__(256) void k_fill(const int* __restrict__ dst,
                                              int* __restrict__ cursor,
                                              int* __restrict__ eidx, int E) {
    int e = blockIdx.x * 256 + threadIdx.x;
    if (e >= E) return;
    int p = atomicAdd(&cursor[dst[e]], 1);
    eidx[p] = e;
}

// ---------------------------------------------------------------------------
// Parallel edge attention: att[e] = dot(t, tanh(h + ef)); segmax via atomicMax
// on order-preserving keys. One wave handles TWO edges; original edge order
// keeps the efeat stream sequential.
// ---------------------------------------------------------------------------
__global__ __launch_bounds__(256) void k_att(const unsigned short* __restrict__ proj,
                                             const float* __restrict__ efeat,
                                             const int* __restrict__ src,
                                             const int* __restrict__ dst,
                                             const int* __restrict__ etype,
                                             float* __restrict__ att,
                                             unsigned* __restrict__ segmax,
                                             int N, int E) {
    const int wid = blockIdx.x * 4 + (threadIdx.x >> 6);
    const int lane = threadIdx.x & 63;
    const int e0 = wid * 2;
    const int e1 = e0 + 1;
    if (e0 >= E) return;
    const bool has1 = (e1 < E);

    int s0 = src[e0], d0 = dst[e0], r0 = etype[e0];
    int s1 = has1 ? src[e1] : s0;
    int d1 = has1 ? dst[e1] : d0;
    int r1 = has1 ? etype[e1] : r0;

    float t0 = bf2f(proj[((size_t)r0 * N + s0) * DIM + lane]);
    float h0 = bf2f(proj[((size_t)r0 * N + d0) * DIM + lane]);
    float t1 = bf2f(proj[((size_t)r1 * N + s1) * DIM + lane]);
    float h1 = bf2f(proj[((size_t)r1 * N + d1) * DIM + lane]);
    float ef0 = efeat[(size_t)e0 * DIM + lane];
    float ef1 = has1 ? efeat[(size_t)e1 * DIM + lane] : 0.f;

    float a0 = t0 * fast_tanh(h0 + ef0);
    float a1 = t1 * fast_tanh(h1 + ef1);
#pragma unroll
    for (int m = 32; m; m >>= 1) {
        a0 += __shfl_xor(a0, m);
        a1 += __shfl_xor(a1, m);
    }
    if (lane == 0) {
        att[e0] = a0;
        unsigned b0 = __float_as_uint(a0);
        atomicMax(&segmax[d0], b0 ^ (unsigned)(((int)b0 >> 31) | 0x80000000));
        if (has1) {
            att[e1] = a1;
            unsigned b1 = __float_as_uint(a1);
            atomicMax(&segmax[d1], b1 ^ (unsigned)(((int)b1 >> 31) | 0x80000000));
        }
    }
}

// ---------------------------------------------------------------------------
// Per-node softmax aggregation + bi-interaction epilogue. Wave per node.
// ---------------------------------------------------------------------------
__global__ __launch_bounds__(256) void k_aggB(const float* __restrict__ att,
                                              const unsigned* __restrict__ segmax,
                                              const float* __restrict__ nfeat,
                                              const int* __restrict__ src,
                                              const int* __restrict__ off,
                                              const int* __restrict__ eidx,
                                              const float* __restrict__ W1,
                                              const float* __restrict__ W2,
                                              float* __restrict__ hn,
                                              float* __restrict__ out,
                                              int N) {
    const int node = blockIdx.x * 4 + (threadIdx.x >> 6);
    if (node >= N) return;
    const int lane = threadIdx.x & 63;

    const int jb = off[node];
    const int je = off[node + 1];

    unsigned key = segmax[node];
    unsigned bits = (key & 0x80000000u) ? (key ^ 0x80000000u) : ~key;
    const float m = __uint_as_float(bits);

    float l = 0.f, acc = 0.f;
    for (int j = jb; j < je; ++j) {
        const int e = eidx[j];
        const int s = src[e];
        float p = __expf(att[e] - m);
        l += p;
        acc = fmaf(p, nfeat[(size_t)s * DIM + lane], acc);
    }

    const float hval = (je > jb) ? acc / l : 0.f;
    hn[(size_t)node * DIM + lane] = hval;

    const float nf = nfeat[(size_t)node * DIM + lane];
    const float v1 = nf + hval;
    const float v2 = nf * hval;
    float o1 = 0.f, o2 = 0.f;
#pragma unroll 8
    for (int d = 0; d < DIM; ++d) {
        float s1 = __shfl(v1, d);
        float s2 = __shfl(v2, d);
        o1 = fmaf(s1, W1[d * DIM + lane], o1);
        o2 = fmaf(s2, W2[d * DIM + lane], o2);
    }
    out[(size_t)node * DIM + lane] =
        (o1 >= 0.f ? o1 : 0.01f * o1) + (o2 >= 0.f ? o2 : 0.01f * o2);
}

extern "C" void kernel_launch(void* const* d_in, const int* in_sizes, int n_in,
                              void* d_out, int out_size, void* d_ws, size_t ws_size,
                              hipStream_t stream) {
    const float* nfeat = (const float*)d_in[0];
    const float* efeat = (const float*)d_in[1];
    const float* relW  = (const float*)d_in[2];
    const float* W1    = (const float*)d_in[3];
    const float* W2    = (const float*)d_in[4];
    const int* src   = (const int*)d_in[5];
    const int* dst   = (const int*)d_in[6];
    const int* etype = (const int*)d_in[7];

    const int N = in_sizes[0] / DIM;
    const int E = in_sizes[5];
    const int R = in_sizes[2] / (DIM * DIM);

    float* out = (float*)d_out;
    float* hn  = out;                      // output 0: h_neighbor (N x 64)
    float* bi  = out + (size_t)N * DIM;    // output 1: out (N x 64)

    // ws: proj bf16 (R*N*64) | deg[N] | segmax[N] | off[N+1] | cursor[N] | eidx[E] | att[E]
    unsigned short* proj = (unsigned short*)d_ws;
    size_t projElems = (size_t)R * N * DIM;
    int* deg         = (int*)(proj + projElems);
    unsigned* segmax = (unsigned*)(deg + N);
    int* off         = (int*)(segmax + N);
    int* cursor      = off + (N + 1);
    int* eidx        = cursor + N;
    float* att       = (float*)(eidx + E);

    (void)hipMemsetAsync(deg, 0, (size_t)2 * N * sizeof(int), stream);  // deg + segmax

    k_hist<<<(E + 255) / 256, 256, 0, stream>>>(dst, deg, E);
    k_scan<<<1, 1024, 0, stream>>>(deg, off, cursor, N, E);
    k_fill<<<(E + 255) / 256, 256, 0, stream>>>(dst, cursor, eidx, E);

    dim3 gProj((N + 63) / 64, R);
    k_proj<<<gProj, 256, 0, stream>>>(nfeat, relW, proj, N);

    k_att<<<(E / 2 + 3) / 4 + 1, 256, 0, stream>>>(proj, efeat, src, dst, etype,
                                                   att, segmax, N, E);

    k_aggB<<<(N + 3) / 4, 256, 0, stream>>>(att, segmax, nfeat, src, off, eidx,
                                            W1, W2, hn, bi, N);
}

// Round 6
// 634.241 us; speedup vs baseline: 1.6044x; 1.2528x over previous
//
#include <hip/hip_runtime.h>
#include <math.h>

// KGATConv: N=50000, E=800000, D=64, R=16, fp32.
// R6: thread-per-edge k_att (in-register dot, CSR-slot scatter write, no
// atomics/shuffles) + edge-parallel k_aggB (coalesced segment loads, exact
// wave-max, shuffle-broadcast gathers) + parallel 3-kernel scan.
// k_proj stays MFMA (fp16 in, fp32 acc, bf16 out).

#define DIM 64
#define PA 72

typedef _Float16 half8 __attribute__((ext_vector_type(8)));
typedef float f32x4 __attribute__((ext_vector_type(4)));

__device__ __forceinline__ float4 f4zero() { return make_float4(0.f, 0.f, 0.f, 0.f); }

__device__ __forceinline__ unsigned short f2bf(float x) {
    unsigned u = __float_as_uint(x);
    u += 0x7FFFu + ((u >> 16) & 1u);   // RNE
    return (unsigned short)(u >> 16);
}

__device__ __forceinline__ float fast_tanh(float x) {
    float ex = __expf(2.0f * x);
    return 1.0f - 2.0f / (ex + 1.0f);
}

// unpack 8 bf16 (in a uint4) to fp32
__device__ __forceinline__ void bf8up(uint4 u, float* f) {
    f[0] = __uint_as_float(u.x << 16);
    f[1] = __uint_as_float(u.x & 0xFFFF0000u);
    f[2] = __uint_as_float(u.y << 16);
    f[3] = __uint_as_float(u.y & 0xFFFF0000u);
    f[4] = __uint_as_float(u.z << 16);
    f[5] = __uint_as_float(u.z & 0xFFFF0000u);
    f[6] = __uint_as_float(u.w << 16);
    f[7] = __uint_as_float(u.w & 0xFFFF0000u);
}

// ---------------------------------------------------------------------------
// proj[r,n,:] = bf16( nfeat[n,:] @ relW[r,:,:] ) via mfma_f32_16x16x32_f16
// ---------------------------------------------------------------------------
__global__ __launch_bounds__(256) void k_proj(const float* __restrict__ nfeat,
                                              const float* __restrict__ relW,
                                              unsigned short* __restrict__ proj,
                                              int N) {
    __shared__ _Float16 shA[64 * PA];
    __shared__ _Float16 shB[64 * PA];

    const int tx = threadIdx.x;
    const int r = blockIdx.y;
    const int n0 = blockIdx.x * 64;

    const float4* nf4 = (const float4*)(nfeat + (size_t)n0 * DIM);
#pragma unroll
    for (int i = 0; i < 4; ++i) {
        int idx = tx + 256 * i;
        int row = idx >> 4, c = idx & 15;
        float4 v = (n0 + row < N) ? nf4[idx] : f4zero();
        _Float16* p = &shA[row * PA + c * 4];
        p[0] = (_Float16)v.x; p[1] = (_Float16)v.y;
        p[2] = (_Float16)v.z; p[3] = (_Float16)v.w;
    }
    const float4* Wr4 = (const float4*)(relW + (size_t)r * DIM * DIM);
#pragma unroll
    for (int i = 0; i < 4; ++i) {
        int idx = tx + 256 * i;
        int d = idx >> 4, c = (idx & 15) * 4;
        float4 v = Wr4[idx];
        shB[(c + 0) * PA + d] = (_Float16)v.x;
        shB[(c + 1) * PA + d] = (_Float16)v.y;
        shB[(c + 2) * PA + d] = (_Float16)v.z;
        shB[(c + 3) * PA + d] = (_Float16)v.w;
    }
    __syncthreads();

    const int w = tx >> 6;
    const int lane = tx & 63;
    const int lm = lane & 15;
    const int lq = lane >> 4;
    const int m0 = w * 16;

    half8 a0 = *(const half8*)&shA[(m0 + lm) * PA + 0 * 32 + lq * 8];
    half8 a1 = *(const half8*)&shA[(m0 + lm) * PA + 1 * 32 + lq * 8];

    f32x4 acc[4];
#pragma unroll
    for (int ct = 0; ct < 4; ++ct) {
        half8 b0 = *(const half8*)&shB[(ct * 16 + lm) * PA + 0 * 32 + lq * 8];
        half8 b1 = *(const half8*)&shB[(ct * 16 + lm) * PA + 1 * 32 + lq * 8];
        f32x4 c = {0.f, 0.f, 0.f, 0.f};
        c = __builtin_amdgcn_mfma_f32_16x16x32_f16(a0, b0, c, 0, 0, 0);
        c = __builtin_amdgcn_mfma_f32_16x16x32_f16(a1, b1, c, 0, 0, 0);
        acc[ct] = c;
    }

    unsigned short* projR = proj + ((size_t)r * N + n0) * DIM;
#pragma unroll
    for (int ct = 0; ct < 4; ++ct) {
#pragma unroll
        for (int i = 0; i < 4; ++i) {
            int row = m0 + lq * 4 + i;
            int col = ct * 16 + lm;
            if (n0 + row < N)
                projR[(size_t)row * DIM + col] = f2bf(acc[ct][i]);
        }
    }
}

// ---------------------------------------------------------------------------
// CSR build: histogram -> 3-kernel coalesced scan -> fill (pos + sorted src)
// ---------------------------------------------------------------------------
__global__ __launch_bounds__(256) void k_hist(const int* __restrict__ dst,
                                              int* __restrict__ deg, int E) {
    int e = blockIdx.x * 256 + threadIdx.x;
    if (e < E) atomicAdd(&deg[dst[e]], 1);
}

__global__ __launch_bounds__(256) void k_scan1(const int* __restrict__ deg,
                                               int* __restrict__ bsum, int N) {
    __shared__ int sh[256];
    int i = blockIdx.x * 256 + threadIdx.x;
    int t = threadIdx.x;
    sh[t] = (i < N) ? deg[i] : 0;
    __syncthreads();
#pragma unroll
    for (int s = 128; s > 0; s >>= 1) {
        if (t < s) sh[t] += sh[t + s];
        __syncthreads();
    }
    if (t == 0) bsum[blockIdx.x] = sh[0];
}

__global__ __launch_bounds__(256) void k_scan2(int* __restrict__ bsum, int nb,
                                               int* __restrict__ offN, int E) {
    __shared__ int sh[256];
    int t = threadIdx.x;
    int v = (t < nb) ? bsum[t] : 0;
    sh[t] = v;
    __syncthreads();
#pragma unroll
    for (int d = 1; d < 256; d <<= 1) {
        int o = (t >= d) ? sh[t - d] : 0;
        __syncthreads();
        sh[t] += o;
        __syncthreads();
    }
    if (t < nb) bsum[t] = sh[t] - v;   // exclusive block prefix
    if (t == 0) offN[0] = E;           // off[N] = E
}

__global__ __launch_bounds__(256) void k_scan3(const int* __restrict__ deg,
                                               const int* __restrict__ bsum,
                                               int* __restrict__ off,
                                               int* __restrict__ cursor, int N) {
    __shared__ int sh[256];
    int i = blockIdx.x * 256 + threadIdx.x;
    int t = threadIdx.x;
    int v = (i < N) ? deg[i] : 0;
    sh[t] = v;
    __syncthreads();
#pragma unroll
    for (int d = 1; d < 256; d <<= 1) {
        int o = (t >= d) ? sh[t - d] : 0;
        __syncthreads();
        sh[t] += o;
        __syncthreads();
    }
    if (i < N) {
        int pre = bsum[blockIdx.x] + sh[t] - v;   // exclusive global prefix
        off[i] = pre;
        cursor[i] = pre;
    }
}

__global__ __launch_bounds__(256) void k_fill(const int* __restrict__ dst,
                                              const int* __restrict__ src,
                                              int* __restrict__ cursor,
                                              int* __restrict__ pos,
                                              int* __restrict__ src_s, int E) {
    int e = blockIdx.x * 256 + threadIdx.x;
    if (e >= E) return;
    int p = atomicAdd(&cursor[dst[e]], 1);
    pos[e] = p;
    src_s[p] = src[e];
}

// ---------------------------------------------------------------------------
// Thread-per-edge attention: att = dot(t, tanh(h + ef)) accumulated
// in-register; written to the edge's CSR slot. No shuffles, no atomics.
// ---------------------------------------------------------------------------
__global__ __launch_bounds__(256) void k_att(const unsigned short* __restrict__ proj,
                                             const float* __restrict__ efeat,
                                             const int* __restrict__ src,
                                             const int* __restrict__ dst,
                                             const int* __restrict__ etype,
                                             const int* __restrict__ pos,
                                             float* __restrict__ att_s,
                                             int N, int E) {
    int e = blockIdx.x * 256 + threadIdx.x;
    if (e >= E) return;
    int s = src[e], d = dst[e], r = etype[e];

    const uint4* tp = (const uint4*)(proj + (size_t)((unsigned)(r * N + s)) * DIM);
    const uint4* hp = (const uint4*)(proj + (size_t)((unsigned)(r * N + d)) * DIM);
    const float4* ef = (const float4*)(efeat + (size_t)e * DIM);

    float dotv = 0.f;
#pragma unroll 4
    for (int kc = 0; kc < 8; ++kc) {      // 8 dims per iteration
        uint4 tu = tp[kc];
        uint4 hu = hp[kc];
        float4 efa = ef[kc * 2 + 0];
        float4 efb = ef[kc * 2 + 1];
        float tf[8], hf[8];
        bf8up(tu, tf);
        bf8up(hu, hf);
        float ev[8] = {efa.x, efa.y, efa.z, efa.w, efb.x, efb.y, efb.z, efb.w};
#pragma unroll
        for (int i = 0; i < 8; ++i)
            dotv = fmaf(tf[i], fast_tanh(hf[i] + ev[i]), dotv);
    }
    att_s[pos[e]] = dotv;
}

// ---------------------------------------------------------------------------
// Per-node softmax + aggregation + bi-interaction. Wave per node; segment
// processed edge-parallel (coalesced att_s/src_s), exact wave max, then
// shuffle-broadcast + independent nfeat gathers.
// ---------------------------------------------------------------------------
__global__ __launch_bounds__(256) void k_aggB(const float* __restrict__ att_s,
                                              const int* __restrict__ src_s,
                                              const float* __restrict__ nfeat,
                                              const int* __restrict__ off,
                                              const float* __restrict__ W1,
                                              const float* __restrict__ W2,
                                              float* __restrict__ hn,
                                              float* __restrict__ out,
                                              int N) {
    const int node = blockIdx.x * 4 + (threadIdx.x >> 6);
    if (node >= N) return;
    const int lane = threadIdx.x & 63;

    const int jb = off[node];
    const int je = off[node + 1];

    // exact segment max (edge-parallel, coalesced)
    float m = -INFINITY;
    for (int j0 = jb; j0 < je; j0 += 64) {
        int j = j0 + lane;
        float a = (j < je) ? att_s[j] : -INFINITY;
        m = fmaxf(m, a);
    }
#pragma unroll
    for (int ms = 32; ms; ms >>= 1) m = fmaxf(m, __shfl_xor(m, ms));

    float pl = 0.f, acc = 0.f;
    for (int j0 = jb; j0 < je; j0 += 64) {
        int j = j0 + lane;
        int cnt = min(64, je - j0);
        float a = (j < je) ? att_s[j] : -INFINITY;
        float p = __expf(a - m);          // inactive lanes: exp(-inf)=0
        int s = (j < je) ? src_s[j] : 0;
        pl += p;
        for (int jj = 0; jj < cnt; ++jj) {
            float pj = __shfl(p, jj);
            int sj = __shfl(s, jj);
            acc = fmaf(pj, nfeat[(size_t)sj * DIM + lane], acc);
        }
    }
#pragma unroll
    for (int ms = 32; ms; ms >>= 1) pl += __shfl_xor(pl, ms);

    const float hval = (je > jb) ? acc / pl : 0.f;
    hn[(size_t)node * DIM + lane] = hval;

    const float nf = nfeat[(size_t)node * DIM + lane];
    const float v1 = nf + hval;
    const float v2 = nf * hval;
    float o1 = 0.f, o2 = 0.f;
#pragma unroll 8
    for (int d = 0; d < DIM; ++d) {
        float s1 = __shfl(v1, d);
        float s2 = __shfl(v2, d);
        o1 = fmaf(s1, W1[d * DIM + lane], o1);
        o2 = fmaf(s2, W2[d * DIM + lane], o2);
    }
    out[(size_t)node * DIM + lane] =
        (o1 >= 0.f ? o1 : 0.01f * o1) + (o2 >= 0.f ? o2 : 0.01f * o2);
}

extern "C" void kernel_launch(void* const* d_in, const int* in_sizes, int n_in,
                              void* d_out, int out_size, void* d_ws, size_t ws_size,
                              hipStream_t stream) {
    const float* nfeat = (const float*)d_in[0];
    const float* efeat = (const float*)d_in[1];
    const float* relW  = (const float*)d_in[2];
    const float* W1    = (const float*)d_in[3];
    const float* W2    = (const float*)d_in[4];
    const int* src   = (const int*)d_in[5];
    const int* dst   = (const int*)d_in[6];
    const int* etype = (const int*)d_in[7];

    const int N = in_sizes[0] / DIM;
    const int E = in_sizes[5];
    const int R = in_sizes[2] / (DIM * DIM);
    const int NB = (N + 255) / 256;   // scan blocks (<=256)

    float* out = (float*)d_out;
    float* hn  = out;
    float* bi  = out + (size_t)N * DIM;

    // ws: proj bf16 | deg[N] | off[N+1] | cursor[N] | bsum[256] | pos[E] | src_s[E] | att_s[E]
    unsigned short* proj = (unsigned short*)d_ws;
    size_t projElems = (size_t)R * N * DIM;
    int* deg    = (int*)(proj + projElems);
    int* off    = deg + N;
    int* cursor = off + (N + 1);
    int* bsum   = cursor + N;
    int* pos    = bsum + 256;
    int* src_s  = pos + E;
    float* att_s = (float*)(src_s + E);

    (void)hipMemsetAsync(deg, 0, (size_t)N * sizeof(int), stream);

    k_hist<<<(E + 255) / 256, 256, 0, stream>>>(dst, deg, E);
    k_scan1<<<NB, 256, 0, stream>>>(deg, bsum, N);
    k_scan2<<<1, 256, 0, stream>>>(bsum, NB, off + N, E);
    k_scan3<<<NB, 256, 0, stream>>>(deg, bsum, off, cursor, N);
    k_fill<<<(E + 255) / 256, 256, 0, stream>>>(dst, src, cursor, pos, src_s, E);

    dim3 gProj((N + 63) / 64, R);
    k_proj<<<gProj, 256, 0, stream>>>(nfeat, relW, proj, N);

    k_att<<<(E + 255) / 256, 256, 0, stream>>>(proj, efeat, src, dst, etype,
                                               pos, att_s, N, E);

    k_aggB<<<(N + 3) / 4, 256, 0, stream>>>(att_s, src_s, nfeat, off,
                                            W1, W2, hn, bi, N);
}